// Round 2
// baseline (256.493 us; speedup 1.0000x reference)
//
#include <hip/hip_runtime.h>

typedef unsigned short u16;
typedef __attribute__((ext_vector_type(8))) __bf16 bf16x8;
typedef __attribute__((ext_vector_type(4))) float f32x4;

#define B_SZ   2
#define S_LEN  2048
#define E_DIM  1024
#define NHEAD  16
#define HD     64
#define KDIM   1024
#define NOUT   4096   // q|k|v|g concatenated

__device__ __forceinline__ float bf2f(u16 u){
  union { unsigned int i; float f; } c; c.i = ((unsigned int)u) << 16; return c.f;
}
__device__ __forceinline__ u16 f2bf(float f){
  union { float f; unsigned int i; } c; c.f = f;
  return (u16)((c.i + 0x7FFFu + ((c.i >> 16) & 1u)) >> 16);
}
__device__ __forceinline__ void gl2lds16(const void* g, void* l){
  __builtin_amdgcn_global_load_lds((const __attribute__((address_space(1))) void*)g,
                                   (__attribute__((address_space(3))) void*)l, 16, 0, 0);
}

// ---------------- cast x: fp32 -> bf16 ----------------
__global__ __launch_bounds__(256) void castx_kernel(const float* __restrict__ x, u16* __restrict__ xb){
  size_t base = ((size_t)blockIdx.x * 256 + threadIdx.x) * 16;
  float f[16];
  #pragma unroll
  for (int c = 0; c < 4; c++) *(float4*)&f[c * 4] = *(const float4*)&x[base + c * 4];
  u16 o[16];
  #pragma unroll
  for (int i = 0; i < 16; i++) o[i] = f2bf(f[i]);
  *(uint4*)&xb[base]     = *(uint4*)&o[0];
  *(uint4*)&xb[base + 8] = *(uint4*)&o[8];
}

// ---------------- W transpose + cast: WT[z*1024 + n][k] = bf16(W_z[k][n]) ----------------
__global__ __launch_bounds__(256) void wtrans_kernel(const float* __restrict__ Wq, const float* __restrict__ Wk,
                                                     const float* __restrict__ Wv, const float* __restrict__ Wg,
                                                     u16* __restrict__ WT){
  const float* Ws[4] = {Wq, Wk, Wv, Wg};
  const float* W = Ws[blockIdx.z];
  int n0 = blockIdx.x * 64, k0 = blockIdx.y * 64;
  __shared__ u16 tile[64][66];
  int t = threadIdx.x;
  int r = t >> 2, cg = (t & 3) * 16;
  const float* src = W + (size_t)(k0 + r) * E_DIM + n0 + cg;
  float f[16];
  #pragma unroll
  for (int c = 0; c < 4; c++) *(float4*)&f[c * 4] = *(const float4*)&src[c * 4];
  #pragma unroll
  for (int i = 0; i < 16; i++) tile[r][cg + i] = f2bf(f[i]);
  __syncthreads();
  u16 ov[16];
  #pragma unroll
  for (int i = 0; i < 16; i++) ov[i] = tile[cg + i][r];
  u16* dst = WT + (size_t)(blockIdx.z * E_DIM + n0 + r) * KDIM + k0 + cg;
  *(uint4*)&dst[0] = *(uint4*)&ov[0];
  *(uint4*)&dst[8] = *(uint4*)&ov[8];
}

// ---------------- fused QKVG GEMM: C[4096 tok][4096] = xb @ [Wq|Wk|Wv|Wg] (bf16) ----------------
__global__ __launch_bounds__(256) void gemm_kernel(const u16* __restrict__ A, const u16* __restrict__ Bt,
                                                   u16* __restrict__ C){
  __shared__ __align__(16) u16 As[128 * 64];
  __shared__ __align__(16) u16 Bs[128 * 64];
  int m0 = blockIdx.y * 128, n0 = blockIdx.x * 128;
  int t = threadIdx.x;
  int wave = t >> 6, lane = t & 63;
  int l15 = lane & 15, quad = lane >> 4;
  int r0 = (wave & 1) * 64, c0 = (wave >> 1) * 64;
  f32x4 acc[4][4];
  #pragma unroll
  for (int i = 0; i < 4; i++)
    #pragma unroll
    for (int j = 0; j < 4; j++) acc[i][j] = (f32x4){0.f, 0.f, 0.f, 0.f};

  for (int k0 = 0; k0 < KDIM; k0 += 64){
    __syncthreads();
    #pragma unroll
    for (int c = 0; c < 4; c++){
      int L = c * 256 + t;
      gl2lds16(A + (size_t)(m0 + (L >> 3)) * KDIM + k0 + (L & 7) * 8, &As[L * 8]);
    }
    #pragma unroll
    for (int c = 0; c < 4; c++){
      int L = c * 256 + t;
      gl2lds16(Bt + (size_t)(n0 + (L >> 3)) * KDIM + k0 + (L & 7) * 8, &Bs[L * 8]);
    }
    __syncthreads();
    #pragma unroll
    for (int kk = 0; kk < 2; kk++){
      bf16x8 a[4], b[4];
      #pragma unroll
      for (int i = 0; i < 4; i++) a[i] = *(const bf16x8*)&As[(r0 + i * 16 + l15) * 64 + kk * 32 + quad * 8];
      #pragma unroll
      for (int j = 0; j < 4; j++) b[j] = *(const bf16x8*)&Bs[(c0 + j * 16 + l15) * 64 + kk * 32 + quad * 8];
      #pragma unroll
      for (int i = 0; i < 4; i++)
        #pragma unroll
        for (int j = 0; j < 4; j++)
          acc[i][j] = __builtin_amdgcn_mfma_f32_16x16x32_bf16(a[i], b[j], acc[i][j], 0, 0, 0);
    }
  }
  // C/D layout: col = lane&15, row = quad*4 + reg  [m89-verified]
  #pragma unroll
  for (int i = 0; i < 4; i++){
    int row = m0 + r0 + i * 16 + quad * 4;
    #pragma unroll
    for (int j = 0; j < 4; j++){
      int col = n0 + c0 + j * 16 + l15;
      #pragma unroll
      for (int r = 0; r < 4; r++)
        C[(size_t)(row + r) * NOUT + col] = f2bf(acc[i][j][r]);
    }
  }
}

// ---------------- rotary shift + head-major transpose (bf16 in/out) ----------------
// qr,kr: (B*H, S, D) ; vt: (B*H, D, S) ; k folds E^-0.5.
__global__ __launch_bounds__(256) void shift_kernel(const u16* __restrict__ qkvg,
                                                    u16* __restrict__ qr, u16* __restrict__ kr,
                                                    u16* __restrict__ vt){
  int sb = blockIdx.x, bh = blockIdx.y;
  int s0 = sb * 64;
  int t = threadIdx.x;
  int sl = t >> 2, dg = (t & 3) * 16;
  int s = s0 + sl;
  int h = bh & 15;
  size_t token = (size_t)(bh >> 4) * S_LEN + s;
  size_t base = token * NOUT + h * HD + dg;
  u16 qv[16], kv[16], vv[16];
  *(uint4*)&qv[0] = *(const uint4*)&qkvg[base];
  *(uint4*)&qv[8] = *(const uint4*)&qkvg[base + 8];
  *(uint4*)&kv[0] = *(const uint4*)&qkvg[base + 1024];
  *(uint4*)&kv[8] = *(const uint4*)&qkvg[base + 1024 + 8];
  *(uint4*)&vv[0] = *(const uint4*)&qkvg[base + 2048];
  *(uint4*)&vv[8] = *(const uint4*)&qkvg[base + 2048 + 8];
  u16 qo[16], ko[16];
  #pragma unroll
  for (int i = 0; i < 8; i++){
    int dd = dg + 2 * i;
    // angle a_i = 10000^(-(d/2)/31)  (linspace(0,1,32) step = 1/31)
    float a = exp2f(-(float)(dd >> 1) * (13.287712379549449f / 31.0f));
    float ang = (float)s * a;
    float sn = sinf(ang), cs = cosf(ang);
    float qe = bf2f(qv[2 * i]), qd = bf2f(qv[2 * i + 1]);
    qo[2 * i]     = f2bf(qe * cs - qd * sn);
    qo[2 * i + 1] = f2bf(qd * cs + qe * sn);
    float ke = bf2f(kv[2 * i]) * 0.03125f, kd = bf2f(kv[2 * i + 1]) * 0.03125f;
    ko[2 * i]     = f2bf(ke * cs - kd * sn);
    ko[2 * i + 1] = f2bf(kd * cs + ke * sn);
  }
  size_t dsto = ((size_t)bh * S_LEN + s) * HD + dg;
  *(uint4*)&qr[dsto]     = *(uint4*)&qo[0];
  *(uint4*)&qr[dsto + 8] = *(uint4*)&qo[8];
  *(uint4*)&kr[dsto]     = *(uint4*)&ko[0];
  *(uint4*)&kr[dsto + 8] = *(uint4*)&ko[8];
  // v transpose via LDS
  __shared__ u16 vs[64][66];
  #pragma unroll
  for (int i = 0; i < 16; i++) vs[sl][dg + i] = vv[i];
  __syncthreads();
  int d = t >> 2, jg = (t & 3) * 16;
  u16 ov[16];
  #pragma unroll
  for (int i = 0; i < 16; i++) ov[i] = vs[jg + i][d];
  size_t vdst = ((size_t)bh * HD + d) * S_LEN + s0 + jg;
  *(uint4*)&vt[vdst]     = *(uint4*)&ov[0];
  *(uint4*)&vt[vdst + 8] = *(uint4*)&ov[8];
}

// ---------------- fused retention: S=QK^T, decay mask, abs-denom, PV, RMS, SiLU(g) ----------------
__global__ __launch_bounds__(256) void retention_kernel(const u16* __restrict__ qr, const u16* __restrict__ kr,
                                                        const u16* __restrict__ vt, const u16* __restrict__ qkvg,
                                                        float* __restrict__ out){
  int qb = blockIdx.x, bh = blockIdx.y;
  int b = bh >> 4, h = bh & 15;
  int q0 = qb * 64;
  __shared__ __align__(16) u16 Ps[64 * 64];  // stages Q first, then P round-trip
  __shared__ __align__(16) u16 Ks[64 * 64];
  __shared__ __align__(16) u16 Vs[64 * 64];  // [d][j]
  int t = threadIdx.x, wave = t >> 6, lane = t & 63;
  int l15 = lane & 15, quad = lane >> 4;
  int r0 = wave * 16;

  float decay = log1pf(-exp2f(-5.0f - (float)h));  // ln(gamma_h), accurate near 0

  // stage Q (8 KB contiguous)
  const u16* qbase = qr + ((size_t)bh * S_LEN + q0) * HD;
  #pragma unroll
  for (int c = 0; c < 2; c++){
    int L = c * 256 + t;
    gl2lds16(qbase + L * 8, &Ps[L * 8]);
  }
  __syncthreads();
  bf16x8 aq0 = *(const bf16x8*)&Ps[(r0 + l15) * 64 + quad * 8];
  bf16x8 aq1 = *(const bf16x8*)&Ps[(r0 + l15) * 64 + 32 + quad * 8];
  __syncthreads();  // everyone done reading Q before Ps reuse

  int qi[4]; float rinv[4];
  float em1d = expm1f(decay);
  #pragma unroll
  for (int r = 0; r < 4; r++){
    qi[r] = q0 + r0 + quad * 4 + r;
    float rowsum = expm1f((float)(qi[r] + 1) * decay) / em1d;  // (1-g^(i+1))/(1-g)
    rinv[r] = rsqrtf(rowsum);
  }
  f32x4 o[4];
  #pragma unroll
  for (int dt = 0; dt < 4; dt++) o[dt] = (f32x4){0.f, 0.f, 0.f, 0.f};
  float babs[4] = {0.f, 0.f, 0.f, 0.f};

  // skip K-blocks whose max decay factor < e^-23 (~1e-10 relative contribution)
  int kb_start = 0;
  {
    float window = 23.0f / (-decay);
    int kmin = q0 - 63 - (int)window;
    if (kmin > 0) kb_start = kmin >> 6;
  }

  for (int kb = kb_start; kb <= qb; kb++){
    int k0 = kb * 64;
    __syncthreads();
    const u16* kbase = kr + ((size_t)bh * S_LEN + k0) * HD;
    #pragma unroll
    for (int c = 0; c < 2; c++){
      int L = c * 256 + t;
      gl2lds16(kbase + L * 8, &Ks[L * 8]);
    }
    const u16* vbase = vt + (size_t)bh * HD * S_LEN + k0;
    #pragma unroll
    for (int c = 0; c < 2; c++){
      int L = c * 256 + t;
      gl2lds16(vbase + (size_t)(L >> 3) * S_LEN + (L & 7) * 8, &Vs[L * 8]);
    }
    __syncthreads();
    // S = Q K^T  (wave strip: rows r0..r0+15, all 64 cols)
    f32x4 s4[4];
    #pragma unroll
    for (int ct = 0; ct < 4; ct++){
      bf16x8 b0 = *(const bf16x8*)&Ks[(ct * 16 + l15) * 64 + quad * 8];
      bf16x8 b1 = *(const bf16x8*)&Ks[(ct * 16 + l15) * 64 + 32 + quad * 8];
      f32x4 z = (f32x4){0.f, 0.f, 0.f, 0.f};
      z = __builtin_amdgcn_mfma_f32_16x16x32_bf16(aq0, b0, z, 0, 0, 0);
      z = __builtin_amdgcn_mfma_f32_16x16x32_bf16(aq1, b1, z, 0, 0, 0);
      s4[ct] = z;
    }
    // mask + abs accum + P to LDS (C-layout -> A-layout round trip)
    #pragma unroll
    for (int ct = 0; ct < 4; ct++){
      int kj = k0 + ct * 16 + l15;
      #pragma unroll
      for (int r = 0; r < 4; r++){
        float p = 0.f;
        if (kj <= qi[r])
          p = s4[ct][r] * __expf((float)(qi[r] - kj) * decay) * rinv[r];
        babs[r] += fabsf(p);
        Ps[(r0 + quad * 4 + r) * 64 + ct * 16 + l15] = f2bf(p);
      }
    }
    __syncthreads();
    // O += P V
    bf16x8 ap0 = *(const bf16x8*)&Ps[(r0 + l15) * 64 + quad * 8];
    bf16x8 ap1 = *(const bf16x8*)&Ps[(r0 + l15) * 64 + 32 + quad * 8];
    #pragma unroll
    for (int dt = 0; dt < 4; dt++){
      bf16x8 v0 = *(const bf16x8*)&Vs[(dt * 16 + l15) * 64 + quad * 8];
      bf16x8 v1 = *(const bf16x8*)&Vs[(dt * 16 + l15) * 64 + 32 + quad * 8];
      o[dt] = __builtin_amdgcn_mfma_f32_16x16x32_bf16(ap0, v0, o[dt], 0, 0, 0);
      o[dt] = __builtin_amdgcn_mfma_f32_16x16x32_bf16(ap1, v1, o[dt], 0, 0, 0);
    }
  }

  // ---- epilogue: denom clip, RMS over D, SiLU(g) gate ----
  #pragma unroll
  for (int r = 0; r < 4; r++){
    float v = babs[r];
    v += __shfl_xor(v, 1); v += __shfl_xor(v, 2);
    v += __shfl_xor(v, 4); v += __shfl_xor(v, 8);
    float den = fminf(fmaxf(v, 1.0f), 50000.0f);
    babs[r] = 1.0f / den;
  }
  float ssq[4] = {0.f, 0.f, 0.f, 0.f};
  #pragma unroll
  for (int dt = 0; dt < 4; dt++)
    #pragma unroll
    for (int r = 0; r < 4; r++){
      float v = o[dt][r] * babs[r];
      o[dt][r] = v;
      ssq[r] += v * v;
    }
  #pragma unroll
  for (int r = 0; r < 4; r++){
    float v = ssq[r];
    v += __shfl_xor(v, 1); v += __shfl_xor(v, 2);
    v += __shfl_xor(v, 4); v += __shfl_xor(v, 8);
    ssq[r] = rsqrtf(v * (1.0f / 64.0f) + 1e-6f);
  }
  #pragma unroll
  for (int r = 0; r < 4; r++){
    int s = q0 + r0 + quad * 4 + r;
    size_t gbase = ((size_t)b * S_LEN + s) * NOUT + 3072 + h * HD;
    size_t obase = ((size_t)b * S_LEN + s) * E_DIM + h * HD;
    #pragma unroll
    for (int dt = 0; dt < 4; dt++){
      int d = dt * 16 + l15;
      float gv = bf2f(qkvg[gbase + d]);
      float sg = gv / (1.0f + __expf(-gv));  // silu
      out[obase + d] = o[dt][r] * ssq[r] * sg;
    }
  }
}

extern "C" void kernel_launch(void* const* d_in, const int* in_sizes, int n_in,
                              void* d_out, int out_size, void* d_ws, size_t ws_size,
                              hipStream_t stream){
  const float* x  = (const float*)d_in[0];
  const float* Wq = (const float*)d_in[1];
  const float* Wk = (const float*)d_in[2];
  const float* Wv = (const float*)d_in[3];
  const float* Wg = (const float*)d_in[4];
  float* out = (float*)d_out;
  char* ws = (char*)d_ws;
  // ws layout (bytes), with dead-buffer overlays (stream-ordered kernels make this safe):
  //   R0 [0,8MB):   xb (cast of x, dead after gemm)  -> qr
  //   R1 [8,16MB):  WT (dead after gemm)             -> vt
  //   R2 [16,48MB): qkvg (g section live to the end)
  //   R3 [48,56MB): kr
  u16* xb   = (u16*)(ws);
  u16* WT   = (u16*)(ws + (8ull  << 20));
  u16* qkvg = (u16*)(ws + (16ull << 20));
  u16* qrp  = (u16*)(ws);
  u16* vtp  = (u16*)(ws + (8ull  << 20));
  u16* krp  = (u16*)(ws + (48ull << 20));

  castx_kernel    <<<dim3(1024),      256, 0, stream>>>(x, xb);
  wtrans_kernel   <<<dim3(16, 16, 4), 256, 0, stream>>>(Wq, Wk, Wv, Wg, WT);
  gemm_kernel     <<<dim3(32, 32),    256, 0, stream>>>(xb, WT, qkvg);
  shift_kernel    <<<dim3(32, 32),    256, 0, stream>>>(qkvg, qrp, krp, vtp);
  retention_kernel<<<dim3(32, 32),    256, 0, stream>>>(qrp, krp, vtp, qkvg, out);
}